// Round 6
// baseline (262.228 us; speedup 1.0000x reference)
//
#include <hip/hip_runtime.h>
#include <hip/hip_cooperative_groups.h>
#include <math.h>

namespace cg = cooperative_groups;

#define V 8
#define B 128
#define P 512
#define NE 75

static constexpr float NU = 0.1f;
static constexpr float EPS = 1e-5f;
static constexpr float INV_SQRT2 = 0.70710678118654752440f;
static constexpr float L2E = 1.4426950408889634f;  // log2(e)

typedef float v4f __attribute__((ext_vector_type(4)));

__device__ __forceinline__ float fast_exp2(float x) {
#if __has_builtin(__builtin_amdgcn_exp2f)
  return __builtin_amdgcn_exp2f(x);
#else
  return exp2f(x);
#endif
}

__device__ __forceinline__ v4f v4fma(v4f a, v4f b, v4f c) {
#if __has_builtin(__builtin_elementwise_fma)
  return __builtin_elementwise_fma(a, b, c);
#else
  v4f r;
  r.x = fmaf(a.x, b.x, c.x); r.y = fmaf(a.y, b.y, c.y);
  r.z = fmaf(a.z, b.z, c.z); r.w = fmaf(a.w, b.w, c.w);
  return r;
#endif
}

// Agent-scope (device-coherent, cross-XCD-safe) load/store for intermediates.
template <bool COH>
__device__ __forceinline__ float gld(const float* p) {
  if constexpr (COH)
    return __hip_atomic_load(p, __ATOMIC_RELAXED, __HIP_MEMORY_SCOPE_AGENT);
  else
    return *p;
}
template <bool COH>
__device__ __forceinline__ void gst(float* p, float v) {
  if constexpr (COH)
    __hip_atomic_store(p, v, __ATOMIC_RELAXED, __HIP_MEMORY_SCOPE_AGENT);
  else
    *p = v;
}

struct Params {
  const float2* pts2;  const int* lengths;
  const float* centers; const float* sharp;
  const float* c1w; const float* c2w; const float* l1w; const float* l1b;
  const float* g1;  const float* b1;  const float* l2w; const float* l2b;
  const float* fc1w; const float* fc1b; const float* g2; const float* b2;
  const float* fc2w; const float* fc2b;
  float* A1t; float* Yt; float* out;
};

struct Sh {
  float sS[3][P], sY[3][P], sS2[3][P], sY2[3][P];  // 24 KB SoA
  float slb[3][NE];
  float hn[NE];
};

// ---------------------------------------------------------------------------
// Phase 1: transform + masked Gaussian sums + conv1 -> conv2 -> max -> l1.
// One tile = one (i,b). 256 threads, 225 active as (j,n).
// ---------------------------------------------------------------------------
template <bool COH>
__device__ __forceinline__ void phase1(const Params& Q, int i, int b, int t,
                                       Sh& sh) {
  int d0 = (i + V - 1) & (V - 1), d1 = i, d2 = (i + 1) & (V - 1);
  int len0 = Q.lengths[d0 * B + b];
  int len1 = Q.lengths[d1 * B + b];
  int len2 = Q.lengths[d2 * B + b];

  for (int u = t; u < 3 * P; u += 256) {
    int jj = u >> 9;
    int pp = u & (P - 1);
    int d   = (jj == 0) ? d0 : (jj == 1) ? d1 : d2;
    int len = (jj == 0) ? len0 : (jj == 1) ? len1 : len2;
    float2 q = Q.pts2[((size_t)d * B + b) * P + pp];
    float s = (q.x + q.y) * INV_SQRT2;
    float y = (q.y - q.x) * INV_SQRT2;
    if (y <= NU) y = __logf(fmaxf(y, 1e-12f) * 10.0f) + NU;
    if (pp >= len) { s = 1e9f; y = 1e9f; }  // exp2 -> 0 exactly
    sh.sS[jj][pp] = s;
    sh.sY[jj][pp] = y;
    sh.sS2[jj][pp] = s * s;
    sh.sY2[jj][pp] = y * y;
  }

  int j = (t >= 150) ? 2 : (t >= 75 ? 1 : 0);
  int n = t - j * 75;
  bool active = (t < 225);
  if (!active) { j = 2; n = 74; }

  int ci = (i * NE + n) * 2;
  float a  = Q.sharp[ci],   c  = Q.sharp[ci + 1];
  float cs = Q.centers[ci], cy = Q.centers[ci + 1];
  float nA = -a * L2E;
  float nC = -c * L2E;
  float Bsc = 2.0f * a * cs * L2E;
  float Byc = 2.0f * c * cy * L2E;
  float nD = -(a * cs * cs + c * cy * cy) * L2E;
  v4f nA4 = {nA, nA, nA, nA}, nC4 = {nC, nC, nC, nC};
  v4f Bs4 = {Bsc, Bsc, Bsc, Bsc}, By4 = {Byc, Byc, Byc, Byc};
  v4f nD4 = {nD, nD, nD, nD};

  // wave-uniform trip count
  int w = t >> 6;
  int mx = (w == 0) ? len0
         : (w == 1) ? max(len0, len1)
         : (w == 2) ? max(len1, len2) : len2;
  int trip = (mx + 7) & ~7;

  __syncthreads();

  float ac0 = 0.f, ac1 = 0.f, ac2 = 0.f, ac3 = 0.f;
  float ac4 = 0.f, ac5 = 0.f, ac6 = 0.f, ac7 = 0.f;
  for (int p = 0; p < trip; p += 8) {
    v4f Sa = *(const v4f*)&sh.sS[j][p],  Sb = *(const v4f*)&sh.sS[j][p + 4];
    v4f Ya = *(const v4f*)&sh.sY[j][p],  Yb = *(const v4f*)&sh.sY[j][p + 4];
    v4f Qa = *(const v4f*)&sh.sS2[j][p], Qb = *(const v4f*)&sh.sS2[j][p + 4];
    v4f Ra = *(const v4f*)&sh.sY2[j][p], Rb = *(const v4f*)&sh.sY2[j][p + 4];
    v4f argA = v4fma(Qa, nA4, v4fma(Ra, nC4, v4fma(Sa, Bs4, v4fma(Ya, By4, nD4))));
    v4f argB = v4fma(Qb, nA4, v4fma(Rb, nC4, v4fma(Sb, Bs4, v4fma(Yb, By4, nD4))));
    ac0 += fast_exp2(argA.x);
    ac1 += fast_exp2(argA.y);
    ac2 += fast_exp2(argA.z);
    ac3 += fast_exp2(argA.w);
    ac4 += fast_exp2(argB.x);
    ac5 += fast_exp2(argB.y);
    ac6 += fast_exp2(argB.z);
    ac7 += fast_exp2(argB.w);
  }
  float accv = ((ac0 + ac1) + (ac2 + ac3)) + ((ac4 + ac5) + (ac6 + ac7));

  if (active) sh.slb[j][n] = accv;
  __syncthreads();

  if (t < NE) {
    float s0 = sh.slb[0][t], s1 = sh.slb[1][t], s2 = sh.slb[2][t];
    float a0 = 0, a1 = 0, a2 = 0, a3 = 0;
#pragma unroll
    for (int f = 0; f < 16; ++f) {
      float w0 = Q.c1w[(i * 16 + f) * 3 + 0];
      float w1 = Q.c1w[(i * 16 + f) * 3 + 1];
      float w2 = Q.c1w[(i * 16 + f) * 3 + 2];
      float h1 = fmaf(w0, s0, fmaf(w1, s1, w2 * s2));
      a0 = fmaf(Q.c2w[(i * 4 + 0) * 16 + f], h1, a0);
      a1 = fmaf(Q.c2w[(i * 4 + 1) * 16 + f], h1, a1);
      a2 = fmaf(Q.c2w[(i * 4 + 2) * 16 + f], h1, a2);
      a3 = fmaf(Q.c2w[(i * 4 + 3) * 16 + f], h1, a3);
    }
    sh.hn[t] = fmaxf(fmaxf(a0, a1), fmaxf(a2, a3));
  }
  __syncthreads();

  if (t < 25) {
    float acc = Q.l1b[i * 25 + t];
    const float* wgt = Q.l1w + ((size_t)i * 25 + t) * NE;
#pragma unroll 5
    for (int m = 0; m < NE; ++m) acc = fmaf(wgt[m], sh.hn[m], acc);
    gst<COH>(&Q.A1t[((size_t)(i * 25 + t)) * B + b], acc);
  }
}

// ---------------------------------------------------------------------------
// Phase 2: bn1 (redundant per-block batch stats) + l2 + relu + fc1.
// ---------------------------------------------------------------------------
template <bool COH>
__device__ __forceinline__ void phase2(const Params& Q, int b, int t,
                                       float* xin, float* Xl) {
  if (t < 200) {
    const float* col = Q.A1t + (size_t)t * B;
    float s = 0.f, q = 0.f;
#pragma unroll 8
    for (int u = 0; u < B; ++u) {
      float v = gld<COH>(col + u);
      s += v;
      q = fmaf(v, v, q);
    }
    float m = s * (1.0f / B);
    float var = q * (1.0f / B) - m * m;
    float r = rsqrtf(var + EPS);
    float v = gld<COH>(col + b);
    xin[t] = (v - m) * r * Q.g1[t] + Q.b1[t];
  }
  __syncthreads();
  if (t < 200) {
    int i = t / 25;
    float acc = Q.l2b[t];
    const float* w = Q.l2w + (size_t)t * 25;
    const float* x = xin + i * 25;
#pragma unroll
    for (int jj = 0; jj < 25; ++jj) acc = fmaf(w[jj], x[jj], acc);
    Xl[t] = fmaxf(acc, 0.0f);
  }
  __syncthreads();
  if (t < 100) {
    float acc = Q.fc1b[t];
    const float* w = Q.fc1w + (size_t)t * 200;
#pragma unroll 8
    for (int q = 0; q < 200; ++q) acc = fmaf(w[q], Xl[q], acc);
    gst<COH>(&Q.Yt[(size_t)t * B + b], acc);
  }
}

// ---------------------------------------------------------------------------
// Phase 3: bn2 (redundant per-block stats) + fc2 -> out[B,70]
// ---------------------------------------------------------------------------
template <bool COH>
__device__ __forceinline__ void phase3(const Params& Q, int b, int t,
                                       float* yin) {
  if (t < 100) {
    const float* col = Q.Yt + (size_t)t * B;
    float s = 0.f, q = 0.f;
#pragma unroll 8
    for (int u = 0; u < B; ++u) {
      float v = gld<COH>(col + u);
      s += v;
      q = fmaf(v, v, q);
    }
    float m = s * (1.0f / B);
    float var = q * (1.0f / B) - m * m;
    float r = rsqrtf(var + EPS);
    float v = gld<COH>(col + b);
    yin[t] = (v - m) * r * Q.g2[t] + Q.b2[t];
  }
  __syncthreads();
  if (t < 70) {
    float acc = Q.fc2b[t];
    const float* w = Q.fc2w + (size_t)t * 100;
#pragma unroll 4
    for (int m = 0; m < 100; ++m) acc = fmaf(w[m], yin[m], acc);
    Q.out[(size_t)b * 70 + t] = acc;
  }
}

// ---------------------------------------------------------------------------
// Cooperative single-kernel: persistent blocks stride over tiles; two
// grid.syncs replace kernel boundaries. Grid size G <= co-resident capacity
// (host-gated), so the launch cannot be rejected as TooLarge.
// ---------------------------------------------------------------------------
__global__ __launch_bounds__(256, 4) void k_fused(Params Q) {
  __shared__ Sh sh;
  cg::grid_group grid = cg::this_grid();
  int t = threadIdx.x;
  int G = gridDim.x;

  for (int tile = blockIdx.x; tile < V * B; tile += G) {
    __syncthreads();  // protect LDS reuse across persistent iterations
    phase1<true>(Q, tile >> 7, tile & 127, t, sh);
  }
  grid.sync();
  for (int b = blockIdx.x; b < B; b += G) {
    __syncthreads();
    phase2<true>(Q, b, t, &sh.sS[0][0], &sh.sS[1][0]);
  }
  grid.sync();
  for (int b = blockIdx.x; b < B; b += G) {
    __syncthreads();
    phase3<true>(Q, b, t, &sh.sS[2][0]);
  }
}

// ------------------------- fallback 3-kernel path --------------------------
__global__ __launch_bounds__(256, 4) void k_structure(Params Q) {
  __shared__ Sh sh;
  phase1<false>(Q, blockIdx.x >> 7, blockIdx.x & 127, threadIdx.x, sh);
}
__global__ __launch_bounds__(256) void k_tail1(Params Q) {
  __shared__ float xin[200], Xl[200];
  phase2<false>(Q, blockIdx.x, threadIdx.x, xin, Xl);
}
__global__ __launch_bounds__(128) void k_tail2(Params Q) {
  __shared__ float yin[100];
  phase3<false>(Q, blockIdx.x, threadIdx.x, yin);
}

// ---------------------------------------------------------------------------
extern "C" void kernel_launch(void* const* d_in, const int* in_sizes, int n_in,
                              void* d_out, int out_size, void* d_ws, size_t ws_size,
                              hipStream_t stream) {
  Params p;
  p.pts2    = (const float2*)d_in[0];
  p.lengths = (const int*)d_in[1];
  p.centers = (const float*)d_in[2];
  p.sharp   = (const float*)d_in[3];
  p.c1w     = (const float*)d_in[4];
  p.c2w     = (const float*)d_in[5];
  p.l1w     = (const float*)d_in[6];
  p.l1b     = (const float*)d_in[7];
  p.g1      = (const float*)d_in[8];
  p.b1      = (const float*)d_in[9];
  p.l2w     = (const float*)d_in[10];
  p.l2b     = (const float*)d_in[11];
  p.fc1w    = (const float*)d_in[12];
  p.fc1b    = (const float*)d_in[13];
  p.g2      = (const float*)d_in[14];
  p.b2      = (const float*)d_in[15];
  p.fc2w    = (const float*)d_in[16];
  p.fc2b    = (const float*)d_in[17];
  p.A1t = (float*)d_ws;           // [200][128]
  p.Yt  = p.A1t + 200 * B;        // [100][128]
  p.out = (float*)d_out;

  // Host-side capacity gate (pure host queries: safe under graph capture,
  // zero cost at replay, deterministic).
  int occ = 0;
  hipError_t e1 =
      hipOccupancyMaxActiveBlocksPerMultiprocessor(&occ, (const void*)k_fused,
                                                   256, 0);
  int dev = 0;
  hipGetDevice(&dev);
  int ncu = 0;
  hipError_t e2 =
      hipDeviceGetAttribute(&ncu, hipDeviceAttributeMultiprocessorCount, dev);

  hipError_t err = hipErrorUnknown;
  if (e1 == hipSuccess && e2 == hipSuccess && occ > 0 && ncu > 0) {
    int cap = occ * ncu;
    int G = (V * B < cap) ? (V * B) : cap;
    void* args[] = {&p};
    err = hipLaunchCooperativeKernel((void*)k_fused, dim3(G), dim3(256), args,
                                     0, stream);
  }
  if (err != hipSuccess) {
    // Fallback: proven 3-kernel path.
    k_structure<<<dim3(V * B), dim3(256), 0, stream>>>(p);
    k_tail1<<<dim3(B), dim3(256), 0, stream>>>(p);
    k_tail2<<<dim3(B), dim3(128), 0, stream>>>(p);
  }
}

// Round 7
// 45.064 us; speedup vs baseline: 5.8191x; 5.8191x over previous
//
#include <hip/hip_runtime.h>
#include <math.h>

#define V 8
#define B 128
#define P 512
#define NE 75

static constexpr float NU = 0.1f;
static constexpr float EPS = 1e-5f;
static constexpr float INV_SQRT2 = 0.70710678118654752440f;
static constexpr float L2E = 1.4426950408889634f;  // log2(e)

typedef float v4f __attribute__((ext_vector_type(4)));

__device__ __forceinline__ float fast_exp2(float x) {
#if __has_builtin(__builtin_amdgcn_exp2f)
  return __builtin_amdgcn_exp2f(x);
#else
  return exp2f(x);
#endif
}

__device__ __forceinline__ v4f v4fma(v4f a, v4f b, v4f c) {
#if __has_builtin(__builtin_elementwise_fma)
  return __builtin_elementwise_fma(a, b, c);
#else
  v4f r;
  r.x = fmaf(a.x, b.x, c.x); r.y = fmaf(a.y, b.y, c.y);
  r.z = fmaf(a.z, b.z, c.z); r.w = fmaf(a.w, b.w, c.w);
  return r;
#endif
}

// ---------------------------------------------------------------------------
// KA (hot, fused): transform + masked Gaussian structure sums + conv1d(3->16)
//                  -> conv1d(16->4) -> channel-max -> l1(75->25)
// One block per (i,b), 256 threads.
//
// WAVE-UNIFORM-J MAPPING (round-7 change): every full wave reads ONE j slice
// so each hot-loop ds_read_b128 is a single-address broadcast (conflict-free;
// the old t->(j,n) mapping gave waves 1,2 two addresses per read — measured
// ~2.25 conflict-cycles per b128, 3.0M total in the R6 profile):
//   wave0: j=0, n=lane (0..63), trip = len0        (own direction only)
//   wave1: j=1, n=lane,        trip = len1
//   wave2: j=2, n=lane,        trip = len2
//   wave3: lanes 0..32: j=lane/11, n=64+lane%11, trip = max3 (33 active)
// Masked points staged as 1e9 -> arg ~ -1.2e19 -> exp2 -> 0 exactly, so trip
// only needs to be >= the lane's own length.
// ---------------------------------------------------------------------------
__global__ __launch_bounds__(256, 4) void k_structure(
    const float2* __restrict__ pts2,      // [V,B,P] (birth,death)
    const int* __restrict__ lengths,      // [V,B]
    const float* __restrict__ centers,    // [V,NE,2] (transformed)
    const float* __restrict__ sharp,      // [V,NE,2]
    const float* __restrict__ c1w,        // [V,16,3]
    const float* __restrict__ c2w,        // [V,4,16]
    const float* __restrict__ l1w,        // [V,25,NE]
    const float* __restrict__ l1b,        // [V,25]
    float* __restrict__ A1t) {            // [V*25][B]
  int i = blockIdx.x >> 7;
  int b = blockIdx.x & 127;
  int t = threadIdx.x;

  __shared__ float sS[3][P], sY[3][P], sS2[3][P], sY2[3][P];  // 24 KB SoA
  __shared__ float slb[3][NE];
  __shared__ float hn[NE];

  int d0 = (i + V - 1) & (V - 1), d1 = i, d2 = (i + 1) & (V - 1);
  int len0 = lengths[d0 * B + b];
  int len1 = lengths[d1 * B + b];
  int len2 = lengths[d2 * B + b];

  // ---- staging: load+transform 3 directions x 512 points ----
  for (int u = t; u < 3 * P; u += 256) {
    int jj = u >> 9;
    int pp = u & (P - 1);
    int d   = (jj == 0) ? d0 : (jj == 1) ? d1 : d2;
    int len = (jj == 0) ? len0 : (jj == 1) ? len1 : len2;
    float2 q = pts2[((size_t)d * B + b) * P + pp];
    float s = (q.x + q.y) * INV_SQRT2;
    float y = (q.y - q.x) * INV_SQRT2;
    if (y <= NU) y = __logf(fmaxf(y, 1e-12f) * 10.0f) + NU;
    if (pp >= len) { s = 1e9f; y = 1e9f; }  // exp2 -> 0 exactly
    sS[jj][pp] = s;
    sY[jj][pp] = y;
    sS2[jj][pp] = s * s;
    sY2[jj][pp] = y * y;
  }

  // ---- wave-uniform (j,n) mapping ----
  int w = t >> 6, l = t & 63;
  int j, n;
  bool active;
  if (w < 3) {
    j = w;
    n = l;
    active = true;          // centers 0..63 of slice j
  } else {
    active = (l < 33);      // 11 leftover centers x 3 slices
    int jl = l / 11;        // 0,1,2 for l<33; clamp inactives
    if (!active) jl = 2;
    j = jl;
    n = active ? (64 + (l - jl * 11)) : 74;
  }

  int ci = (i * NE + n) * 2;
  float a  = sharp[ci],   c  = sharp[ci + 1];
  float cs = centers[ci], cy = centers[ci + 1];
  float nA = -a * L2E;
  float nC = -c * L2E;
  float Bsc = 2.0f * a * cs * L2E;
  float Byc = 2.0f * c * cy * L2E;
  float nD = -(a * cs * cs + c * cy * cy) * L2E;
  v4f nA4 = {nA, nA, nA, nA}, nC4 = {nC, nC, nC, nC};
  v4f Bs4 = {Bsc, Bsc, Bsc, Bsc}, By4 = {Byc, Byc, Byc, Byc};
  v4f nD4 = {nD, nD, nD, nD};

  // wave-uniform trip count: own direction only for waves 0..2
  int mx = (w == 0) ? len0
         : (w == 1) ? len1
         : (w == 2) ? len2 : max(len0, max(len1, len2));
  int trip = (mx + 7) & ~7;

  __syncthreads();

  float ac0 = 0.f, ac1 = 0.f, ac2 = 0.f, ac3 = 0.f;
  float ac4 = 0.f, ac5 = 0.f, ac6 = 0.f, ac7 = 0.f;
  for (int p = 0; p < trip; p += 8) {
    v4f Sa = *(const v4f*)&sS[j][p],  Sb = *(const v4f*)&sS[j][p + 4];
    v4f Ya = *(const v4f*)&sY[j][p],  Yb = *(const v4f*)&sY[j][p + 4];
    v4f Qa = *(const v4f*)&sS2[j][p], Qb = *(const v4f*)&sS2[j][p + 4];
    v4f Ra = *(const v4f*)&sY2[j][p], Rb = *(const v4f*)&sY2[j][p + 4];
    v4f argA = v4fma(Qa, nA4, v4fma(Ra, nC4, v4fma(Sa, Bs4, v4fma(Ya, By4, nD4))));
    v4f argB = v4fma(Qb, nA4, v4fma(Rb, nC4, v4fma(Sb, Bs4, v4fma(Yb, By4, nD4))));
    ac0 += fast_exp2(argA.x);
    ac1 += fast_exp2(argA.y);
    ac2 += fast_exp2(argA.z);
    ac3 += fast_exp2(argA.w);
    ac4 += fast_exp2(argB.x);
    ac5 += fast_exp2(argB.y);
    ac6 += fast_exp2(argB.z);
    ac7 += fast_exp2(argB.w);
  }
  float accv = ((ac0 + ac1) + (ac2 + ac3)) + ((ac4 + ac5) + (ac6 + ac7));

  if (active) slb[j][n] = accv;
  __syncthreads();

  // ---- head: conv1(3->16) -> conv2(16->4) -> channel-max ----
  if (t < NE) {
    float s0 = slb[0][t], s1 = slb[1][t], s2 = slb[2][t];
    float a0 = 0, a1 = 0, a2 = 0, a3 = 0;
#pragma unroll
    for (int f = 0; f < 16; ++f) {
      float w0 = c1w[(i * 16 + f) * 3 + 0];
      float w1 = c1w[(i * 16 + f) * 3 + 1];
      float w2 = c1w[(i * 16 + f) * 3 + 2];
      float h1 = fmaf(w0, s0, fmaf(w1, s1, w2 * s2));
      a0 = fmaf(c2w[(i * 4 + 0) * 16 + f], h1, a0);
      a1 = fmaf(c2w[(i * 4 + 1) * 16 + f], h1, a1);
      a2 = fmaf(c2w[(i * 4 + 2) * 16 + f], h1, a2);
      a3 = fmaf(c2w[(i * 4 + 3) * 16 + f], h1, a3);
    }
    hn[t] = fmaxf(fmaxf(a0, a1), fmaxf(a2, a3));
  }
  __syncthreads();

  // ---- l1: 25 outputs -> A1t[i*25+k][b] (column layout for tail stats) ----
  if (t < 25) {
    float acc = l1b[i * 25 + t];
    const float* wgt = l1w + ((size_t)i * 25 + t) * NE;
#pragma unroll 5
    for (int m = 0; m < NE; ++m) acc = fmaf(wgt[m], hn[m], acc);
    A1t[((size_t)(i * 25 + t)) * B + b] = acc;
  }
}

// ---------------------------------------------------------------------------
// KB: bn1 (redundant per-block batch stats from L2) + l2(25x25)+relu + fc1.
// One block per b, 256 threads. Yt layout [100][B].
// ---------------------------------------------------------------------------
__global__ __launch_bounds__(256) void k_tail1(
    const float* __restrict__ A1t, const float* __restrict__ g1,
    const float* __restrict__ b1, const float* __restrict__ l2w,
    const float* __restrict__ l2b, const float* __restrict__ fc1w,
    const float* __restrict__ fc1b, float* __restrict__ Yt) {
  int b = blockIdx.x;
  int t = threadIdx.x;
  __shared__ float xin[200];
  __shared__ float Xl[200];

  if (t < 200) {
    const float4* col = (const float4*)(A1t + (size_t)t * B);
    float4 s4 = {0, 0, 0, 0}, q4 = {0, 0, 0, 0};
#pragma unroll
    for (int u = 0; u < B / 4; ++u) {
      float4 v = col[u];
      s4.x += v.x; s4.y += v.y; s4.z += v.z; s4.w += v.w;
      q4.x = fmaf(v.x, v.x, q4.x); q4.y = fmaf(v.y, v.y, q4.y);
      q4.z = fmaf(v.z, v.z, q4.z); q4.w = fmaf(v.w, v.w, q4.w);
    }
    float s = (s4.x + s4.y) + (s4.z + s4.w);
    float q = (q4.x + q4.y) + (q4.z + q4.w);
    float m = s * (1.0f / B);
    float var = q * (1.0f / B) - m * m;
    float r = rsqrtf(var + EPS);
    float v = A1t[(size_t)t * B + b];
    xin[t] = (v - m) * r * g1[t] + b1[t];
  }
  __syncthreads();
  if (t < 200) {
    int i = t / 25;
    float acc = l2b[t];
    const float* w = l2w + (size_t)t * 25;
    const float* x = xin + i * 25;
#pragma unroll
    for (int jj = 0; jj < 25; ++jj) acc = fmaf(w[jj], x[jj], acc);
    Xl[t] = fmaxf(acc, 0.0f);
  }
  __syncthreads();
  if (t < 100) {
    float acc = fc1b[t];
    const float* w = fc1w + (size_t)t * 200;
#pragma unroll 8
    for (int q = 0; q < 200; ++q) acc = fmaf(w[q], Xl[q], acc);
    Yt[(size_t)t * B + b] = acc;
  }
}

// ---------------------------------------------------------------------------
// KC: bn2 (redundant per-block stats) + fc2 -> out[B,70]
// ---------------------------------------------------------------------------
__global__ __launch_bounds__(128) void k_tail2(
    const float* __restrict__ Yt, const float* __restrict__ g2,
    const float* __restrict__ b2, const float* __restrict__ fc2w,
    const float* __restrict__ fc2b, float* __restrict__ out) {
  int b = blockIdx.x;
  int t = threadIdx.x;
  __shared__ float yin[100];
  if (t < 100) {
    const float4* col = (const float4*)(Yt + (size_t)t * B);
    float4 s4 = {0, 0, 0, 0}, q4 = {0, 0, 0, 0};
#pragma unroll
    for (int u = 0; u < B / 4; ++u) {
      float4 v = col[u];
      s4.x += v.x; s4.y += v.y; s4.z += v.z; s4.w += v.w;
      q4.x = fmaf(v.x, v.x, q4.x); q4.y = fmaf(v.y, v.y, q4.y);
      q4.z = fmaf(v.z, v.z, q4.z); q4.w = fmaf(v.w, v.w, q4.w);
    }
    float s = (s4.x + s4.y) + (s4.z + s4.w);
    float q = (q4.x + q4.y) + (q4.z + q4.w);
    float m = s * (1.0f / B);
    float var = q * (1.0f / B) - m * m;
    float r = rsqrtf(var + EPS);
    float v = Yt[(size_t)t * B + b];
    yin[t] = (v - m) * r * g2[t] + b2[t];
  }
  __syncthreads();
  if (t < 70) {
    float acc = fc2b[t];
    const float* w = fc2w + (size_t)t * 100;
#pragma unroll 4
    for (int m = 0; m < 100; ++m) acc = fmaf(w[m], yin[m], acc);
    out[(size_t)b * 70 + t] = acc;
  }
}

// ---------------------------------------------------------------------------
extern "C" void kernel_launch(void* const* d_in, const int* in_sizes, int n_in,
                              void* d_out, int out_size, void* d_ws, size_t ws_size,
                              hipStream_t stream) {
  const float2* pts2   = (const float2*)d_in[0];
  const int*   lengths = (const int*)d_in[1];
  const float* centers = (const float*)d_in[2];
  const float* sharp   = (const float*)d_in[3];
  const float* c1w     = (const float*)d_in[4];
  const float* c2w     = (const float*)d_in[5];
  const float* l1w     = (const float*)d_in[6];
  const float* l1b     = (const float*)d_in[7];
  const float* bn1g    = (const float*)d_in[8];
  const float* bn1b    = (const float*)d_in[9];
  const float* l2w     = (const float*)d_in[10];
  const float* l2b     = (const float*)d_in[11];
  const float* fc1w    = (const float*)d_in[12];
  const float* fc1b    = (const float*)d_in[13];
  const float* fbn_g   = (const float*)d_in[14];
  const float* fbn_b   = (const float*)d_in[15];
  const float* fc2w    = (const float*)d_in[16];
  const float* fc2b    = (const float*)d_in[17];
  float* out = (float*)d_out;

  float* A1t = (float*)d_ws;          // [200][128]
  float* Yt  = A1t + 200 * B;         // [100][128]

  k_structure<<<dim3(V * B), dim3(256), 0, stream>>>(
      pts2, lengths, centers, sharp, c1w, c2w, l1w, l1b, A1t);
  k_tail1<<<dim3(B), dim3(256), 0, stream>>>(
      A1t, bn1g, bn1b, l2w, l2b, fc1w, fc1b, Yt);
  k_tail2<<<dim3(B), dim3(128), 0, stream>>>(
      Yt, fbn_g, fbn_b, fc2w, fc2b, out);
}

// Round 8
// 44.158 us; speedup vs baseline: 5.9384x; 1.0205x over previous
//
#include <hip/hip_runtime.h>
#include <math.h>

#define V 8
#define B 128
#define P 512
#define NE 75

static constexpr float NU = 0.1f;
static constexpr float EPS = 1e-5f;
static constexpr float INV_SQRT2 = 0.70710678118654752440f;
static constexpr float L2E = 1.4426950408889634f;  // log2(e)

typedef float v4f __attribute__((ext_vector_type(4)));

__device__ __forceinline__ float fast_exp2(float x) {
#if __has_builtin(__builtin_amdgcn_exp2f)
  return __builtin_amdgcn_exp2f(x);
#else
  return exp2f(x);
#endif
}

__device__ __forceinline__ v4f v4fma(v4f a, v4f b, v4f c) {
#if __has_builtin(__builtin_elementwise_fma)
  return __builtin_elementwise_fma(a, b, c);
#else
  v4f r;
  r.x = fmaf(a.x, b.x, c.x); r.y = fmaf(a.y, b.y, c.y);
  r.z = fmaf(a.z, b.z, c.z); r.w = fmaf(a.w, b.w, c.w);
  return r;
#endif
}

// ---------------------------------------------------------------------------
// KA (hot, fused): transform + masked Gaussian structure sums + conv1d(3->16)
//                  -> conv1d(16->4) -> channel-max -> l1(75->25)
// One block per (i,b), 256 threads.
//
// ROUND-8 CHANGE: hot loop is LDS-return-BW-bound (broadcast b128 still
// delivers 16 B/lane), so stage only (s,y) = 8 B/pt and fold the squares
// into the fma chain:
//   arg = fma(y, fma(nC,y,By), fma(s, fma(nA,s,Bs), nD))
// Per 8 points: 4 ds_read_b128 + 16 pk_fma + 8 exp2 + 8 add; LDS bytes/pt
// halved (16 -> 8).
//
// Wave-uniform-j mapping (R7, kept): every full wave reads ONE j slice ->
// single-address broadcast reads; wave w in {0,1,2}: j=w, n=lane, trip=len_j;
// wave 3: 33 lanes cover the 11 leftover centers x 3 slices, trip=max3.
// Masked points staged as 1e9 -> arg ~ -1.2e19 -> exp2 -> 0 exactly.
// ---------------------------------------------------------------------------
__global__ __launch_bounds__(256, 4) void k_structure(
    const float2* __restrict__ pts2,      // [V,B,P] (birth,death)
    const int* __restrict__ lengths,      // [V,B]
    const float* __restrict__ centers,    // [V,NE,2] (transformed)
    const float* __restrict__ sharp,      // [V,NE,2]
    const float* __restrict__ c1w,        // [V,16,3]
    const float* __restrict__ c2w,        // [V,4,16]
    const float* __restrict__ l1w,        // [V,25,NE]
    const float* __restrict__ l1b,        // [V,25]
    float* __restrict__ A1t) {            // [V*25][B]
  int i = blockIdx.x >> 7;
  int b = blockIdx.x & 127;
  int t = threadIdx.x;

  __shared__ float sS[3][P], sY[3][P];    // 12 KB SoA (s,y only)
  __shared__ float slb[3][NE];
  __shared__ float hn[NE];

  int d0 = (i + V - 1) & (V - 1), d1 = i, d2 = (i + 1) & (V - 1);
  int len0 = lengths[d0 * B + b];
  int len1 = lengths[d1 * B + b];
  int len2 = lengths[d2 * B + b];

  // ---- staging: load+transform 3 directions x 512 points ----
  for (int u = t; u < 3 * P; u += 256) {
    int jj = u >> 9;
    int pp = u & (P - 1);
    int d   = (jj == 0) ? d0 : (jj == 1) ? d1 : d2;
    int len = (jj == 0) ? len0 : (jj == 1) ? len1 : len2;
    float2 q = pts2[((size_t)d * B + b) * P + pp];
    float s = (q.x + q.y) * INV_SQRT2;
    float y = (q.y - q.x) * INV_SQRT2;
    if (y <= NU) y = __logf(fmaxf(y, 1e-12f) * 10.0f) + NU;
    if (pp >= len) { s = 1e9f; y = 1e9f; }  // exp2 -> 0 exactly
    sS[jj][pp] = s;
    sY[jj][pp] = y;
  }

  // ---- wave-uniform (j,n) mapping ----
  int w = t >> 6, l = t & 63;
  int j, n;
  bool active;
  if (w < 3) {
    j = w;
    n = l;
    active = true;          // centers 0..63 of slice j
  } else {
    active = (l < 33);      // 11 leftover centers x 3 slices
    int jl = l / 11;
    if (!active) jl = 2;
    j = jl;
    n = active ? (64 + (l - jl * 11)) : 74;
  }

  int ci = (i * NE + n) * 2;
  float a  = sharp[ci],   c  = sharp[ci + 1];
  float cs = centers[ci], cy = centers[ci + 1];
  float nA = -a * L2E;
  float nC = -c * L2E;
  float Bsc = 2.0f * a * cs * L2E;
  float Byc = 2.0f * c * cy * L2E;
  float nD = -(a * cs * cs + c * cy * cy) * L2E;
  v4f nA4 = {nA, nA, nA, nA}, nC4 = {nC, nC, nC, nC};
  v4f Bs4 = {Bsc, Bsc, Bsc, Bsc}, By4 = {Byc, Byc, Byc, Byc};
  v4f nD4 = {nD, nD, nD, nD};

  // wave-uniform trip count: own direction only for waves 0..2
  int mx = (w == 0) ? len0
         : (w == 1) ? len1
         : (w == 2) ? len2 : max(len0, max(len1, len2));
  int trip = (mx + 7) & ~7;

  __syncthreads();

  float ac0 = 0.f, ac1 = 0.f, ac2 = 0.f, ac3 = 0.f;
  float ac4 = 0.f, ac5 = 0.f, ac6 = 0.f, ac7 = 0.f;
  for (int p = 0; p < trip; p += 8) {
    v4f Sa = *(const v4f*)&sS[j][p], Sb = *(const v4f*)&sS[j][p + 4];
    v4f Ya = *(const v4f*)&sY[j][p], Yb = *(const v4f*)&sY[j][p + 4];
    // arg = y*(nC*y + By) + (s*(nA*s + Bs) + nD)
    v4f ua = v4fma(nA4, Sa, Bs4), ub = v4fma(nA4, Sb, Bs4);
    v4f va = v4fma(nC4, Ya, By4), vb = v4fma(nC4, Yb, By4);
    v4f ta = v4fma(Sa, ua, nD4),  tb = v4fma(Sb, ub, nD4);
    v4f argA = v4fma(Ya, va, ta), argB = v4fma(Yb, vb, tb);
    ac0 += fast_exp2(argA.x);
    ac1 += fast_exp2(argA.y);
    ac2 += fast_exp2(argA.z);
    ac3 += fast_exp2(argA.w);
    ac4 += fast_exp2(argB.x);
    ac5 += fast_exp2(argB.y);
    ac6 += fast_exp2(argB.z);
    ac7 += fast_exp2(argB.w);
  }
  float accv = ((ac0 + ac1) + (ac2 + ac3)) + ((ac4 + ac5) + (ac6 + ac7));

  if (active) slb[j][n] = accv;
  __syncthreads();

  // ---- head: conv1(3->16) -> conv2(16->4) -> channel-max ----
  if (t < NE) {
    float s0 = slb[0][t], s1 = slb[1][t], s2 = slb[2][t];
    float a0 = 0, a1 = 0, a2 = 0, a3 = 0;
#pragma unroll
    for (int f = 0; f < 16; ++f) {
      float w0 = c1w[(i * 16 + f) * 3 + 0];
      float w1 = c1w[(i * 16 + f) * 3 + 1];
      float w2 = c1w[(i * 16 + f) * 3 + 2];
      float h1 = fmaf(w0, s0, fmaf(w1, s1, w2 * s2));
      a0 = fmaf(c2w[(i * 4 + 0) * 16 + f], h1, a0);
      a1 = fmaf(c2w[(i * 4 + 1) * 16 + f], h1, a1);
      a2 = fmaf(c2w[(i * 4 + 2) * 16 + f], h1, a2);
      a3 = fmaf(c2w[(i * 4 + 3) * 16 + f], h1, a3);
    }
    hn[t] = fmaxf(fmaxf(a0, a1), fmaxf(a2, a3));
  }
  __syncthreads();

  // ---- l1: 25 outputs -> A1t[i*25+k][b] (column layout for tail stats) ----
  if (t < 25) {
    float acc = l1b[i * 25 + t];
    const float* wgt = l1w + ((size_t)i * 25 + t) * NE;
#pragma unroll 5
    for (int m = 0; m < NE; ++m) acc = fmaf(wgt[m], hn[m], acc);
    A1t[((size_t)(i * 25 + t)) * B + b] = acc;
  }
}

// ---------------------------------------------------------------------------
// KB: bn1 (redundant per-block batch stats from L2) + l2(25x25)+relu + fc1.
// One block per b, 256 threads. Yt layout [100][B].
// ---------------------------------------------------------------------------
__global__ __launch_bounds__(256) void k_tail1(
    const float* __restrict__ A1t, const float* __restrict__ g1,
    const float* __restrict__ b1, const float* __restrict__ l2w,
    const float* __restrict__ l2b, const float* __restrict__ fc1w,
    const float* __restrict__ fc1b, float* __restrict__ Yt) {
  int b = blockIdx.x;
  int t = threadIdx.x;
  __shared__ float xin[200];
  __shared__ float Xl[200];

  if (t < 200) {
    const float4* col = (const float4*)(A1t + (size_t)t * B);
    float4 s4 = {0, 0, 0, 0}, q4 = {0, 0, 0, 0};
#pragma unroll
    for (int u = 0; u < B / 4; ++u) {
      float4 v = col[u];
      s4.x += v.x; s4.y += v.y; s4.z += v.z; s4.w += v.w;
      q4.x = fmaf(v.x, v.x, q4.x); q4.y = fmaf(v.y, v.y, q4.y);
      q4.z = fmaf(v.z, v.z, q4.z); q4.w = fmaf(v.w, v.w, q4.w);
    }
    float s = (s4.x + s4.y) + (s4.z + s4.w);
    float q = (q4.x + q4.y) + (q4.z + q4.w);
    float m = s * (1.0f / B);
    float var = q * (1.0f / B) - m * m;
    float r = rsqrtf(var + EPS);
    float v = A1t[(size_t)t * B + b];
    xin[t] = (v - m) * r * g1[t] + b1[t];
  }
  __syncthreads();
  if (t < 200) {
    int i = t / 25;
    float acc = l2b[t];
    const float* w = l2w + (size_t)t * 25;
    const float* x = xin + i * 25;
#pragma unroll
    for (int jj = 0; jj < 25; ++jj) acc = fmaf(w[jj], x[jj], acc);
    Xl[t] = fmaxf(acc, 0.0f);
  }
  __syncthreads();
  if (t < 100) {
    float acc = fc1b[t];
    const float* w = fc1w + (size_t)t * 200;
#pragma unroll 8
    for (int q = 0; q < 200; ++q) acc = fmaf(w[q], Xl[q], acc);
    Yt[(size_t)t * B + b] = acc;
  }
}

// ---------------------------------------------------------------------------
// KC: bn2 (redundant per-block stats) + fc2 -> out[B,70]
// ---------------------------------------------------------------------------
__global__ __launch_bounds__(128) void k_tail2(
    const float* __restrict__ Yt, const float* __restrict__ g2,
    const float* __restrict__ b2, const float* __restrict__ fc2w,
    const float* __restrict__ fc2b, float* __restrict__ out) {
  int b = blockIdx.x;
  int t = threadIdx.x;
  __shared__ float yin[100];
  if (t < 100) {
    const float4* col = (const float4*)(Yt + (size_t)t * B);
    float4 s4 = {0, 0, 0, 0}, q4 = {0, 0, 0, 0};
#pragma unroll
    for (int u = 0; u < B / 4; ++u) {
      float4 v = col[u];
      s4.x += v.x; s4.y += v.y; s4.z += v.z; s4.w += v.w;
      q4.x = fmaf(v.x, v.x, q4.x); q4.y = fmaf(v.y, v.y, q4.y);
      q4.z = fmaf(v.z, v.z, q4.z); q4.w = fmaf(v.w, v.w, q4.w);
    }
    float s = (s4.x + s4.y) + (s4.z + s4.w);
    float q = (q4.x + q4.y) + (q4.z + q4.w);
    float m = s * (1.0f / B);
    float var = q * (1.0f / B) - m * m;
    float r = rsqrtf(var + EPS);
    float v = Yt[(size_t)t * B + b];
    yin[t] = (v - m) * r * g2[t] + b2[t];
  }
  __syncthreads();
  if (t < 70) {
    float acc = fc2b[t];
    const float* w = fc2w + (size_t)t * 100;
#pragma unroll 4
    for (int m = 0; m < 100; ++m) acc = fmaf(w[m], yin[m], acc);
    out[(size_t)b * 70 + t] = acc;
  }
}

// ---------------------------------------------------------------------------
extern "C" void kernel_launch(void* const* d_in, const int* in_sizes, int n_in,
                              void* d_out, int out_size, void* d_ws, size_t ws_size,
                              hipStream_t stream) {
  const float2* pts2   = (const float2*)d_in[0];
  const int*   lengths = (const int*)d_in[1];
  const float* centers = (const float*)d_in[2];
  const float* sharp   = (const float*)d_in[3];
  const float* c1w     = (const float*)d_in[4];
  const float* c2w     = (const float*)d_in[5];
  const float* l1w     = (const float*)d_in[6];
  const float* l1b     = (const float*)d_in[7];
  const float* bn1g    = (const float*)d_in[8];
  const float* bn1b    = (const float*)d_in[9];
  const float* l2w     = (const float*)d_in[10];
  const float* l2b     = (const float*)d_in[11];
  const float* fc1w    = (const float*)d_in[12];
  const float* fc1b    = (const float*)d_in[13];
  const float* fbn_g   = (const float*)d_in[14];
  const float* fbn_b   = (const float*)d_in[15];
  const float* fc2w    = (const float*)d_in[16];
  const float* fc2b    = (const float*)d_in[17];
  float* out = (float*)d_out;

  float* A1t = (float*)d_ws;          // [200][128]
  float* Yt  = A1t + 200 * B;         // [100][128]

  k_structure<<<dim3(V * B), dim3(256), 0, stream>>>(
      pts2, lengths, centers, sharp, c1w, c2w, l1w, l1b, A1t);
  k_tail1<<<dim3(B), dim3(256), 0, stream>>>(
      A1t, bn1g, bn1b, l2w, l2b, fc1w, fc1b, Yt);
  k_tail2<<<dim3(B), dim3(128), 0, stream>>>(
      Yt, fbn_g, fbn_b, fc2w, fc2b, out);
}